// Round 1
// baseline (405.082 us; speedup 1.0000x reference)
//
#include <hip/hip_runtime.h>
#include <math.h>

// Problem dims
constexpr int B   = 16;
constexpr int K   = 64;
constexpr int BK  = B * K;        // 1024
constexpr int IN  = 128;
constexpr int H0  = 192;
constexpr int H1  = 64;
constexpr int UNF = 6;
constexpr float EPS = 1e-8f;
constexpr float DT  = 1.0f / 6.0f;

static __device__ __forceinline__ float fast_sigmoid(float z) {
    // 1/(1+exp(-z)); v_exp_f32 + v_rcp_f32, ~1ulp each.
    // z << 0: exp(-z)=inf -> rcp=0.  z >> 0: exp(-z)=0 -> rcp(1)=1.
    return __builtin_amdgcn_rcpf(1.0f + __expf(-z));
}

// ---------------------------------------------------------------------------
// K1: layer-0 input synapse sums. x is shared by all K particles and all 6
// unfold steps -> only [B,H0] = 16x192 work.
// grid: B blocks x H0 threads.
__global__ __launch_bounds__(H0) void l0_input_kernel(
    const float* __restrict__ x,      // [B, IN]
    const float* __restrict__ iw0,    // [IN, H0]
    const float* __restrict__ isig0,
    const float* __restrict__ imu0,
    const float* __restrict__ ierev0,
    float* __restrict__ in_num,       // [B, H0]
    float* __restrict__ in_den)       // [B, H0]
{
    const int h = threadIdx.x;
    const int b = blockIdx.x;
    __shared__ float xs[IN];
    if (h < IN) xs[h] = x[b * IN + h];
    __syncthreads();

    float num = 0.0f, den = 0.0f;
    for (int i = 0; i < IN; ++i) {
        const int idx = i * H0 + h;
        const float wv = fmaxf(iw0[idx], 0.0f);
        const float z  = isig0[idx] * (xs[i] - imu0[idx]);
        const float a  = wv * fast_sigmoid(z);
        num = fmaf(a, ierev0[idx], num);
        den += a;
    }
    in_num[b * H0 + h] = num;
    in_den[b * H0 + h] = den;
}

// ---------------------------------------------------------------------------
// K2: layer-0 unfold. 256 blocks x 192 threads; each block owns M0=4 particle
// rows (same batch b -> shared in_num/in_den). State v in LDS; recurrent
// params streamed once per i and reused across the 4 rows.
constexpr int M0 = 4;   // rows per block; BK/M0 = 256 blocks
__global__ __launch_bounds__(H0) void l0_unfold_kernel(
    const float* __restrict__ particles,  // [BK, 256]
    const float* __restrict__ noise0,     // [UNF, BK, H0]
    const float* __restrict__ gleak0,     // [H0]
    const float* __restrict__ vleak0,
    const float* __restrict__ cm0,
    const float* __restrict__ w0,         // [H0, H0]
    const float* __restrict__ sig0,
    const float* __restrict__ mu0,
    const float* __restrict__ erev0,
    const float* __restrict__ gdiff0,     // [H0]
    const float* __restrict__ in_num,     // [B, H0]
    const float* __restrict__ in_den,
    float* __restrict__ outp)             // new_particles region: [BK, 256]
{
    const int h   = threadIdx.x;          // 0..191
    const int bk0 = blockIdx.x * M0;
    const int b   = bk0 >> 6;             // /K

    __shared__ float vs[M0][H0];
    #pragma unroll
    for (int m = 0; m < M0; ++m)
        vs[m][h] = particles[(bk0 + m) * 256 + h];

    const float gl    = fmaxf(gleak0[h], 0.0f);
    const float glvl  = gl * vleak0[h];
    const float cinv  = __builtin_amdgcn_rcpf(fmaxf(cm0[h], 0.0f) + EPS);
    const float gd    = gdiff0[h] * sqrtf(DT);
    const float innum = in_num[b * H0 + h];
    const float inden = in_den[b * H0 + h];
    __syncthreads();

    for (int step = 0; step < UNF; ++step) {
        float num[M0], den[M0];
        #pragma unroll
        for (int m = 0; m < M0; ++m) { num[m] = innum; den[m] = inden; }

        for (int i = 0; i < H0; ++i) {
            const int idx = i * H0 + h;
            const float wv = fmaxf(w0[idx], 0.0f);
            const float sg = sig0[idx];
            const float mn = mu0[idx];
            const float er = erev0[idx];
            #pragma unroll
            for (int m = 0; m < M0; ++m) {
                const float a = wv * fast_sigmoid(sg * (vs[m][i] - mn));
                num[m] = fmaf(a, er, num[m]);
                den[m] += a;
            }
        }
        __syncthreads();   // all reads of vs done
        #pragma unroll
        for (int m = 0; m < M0; ++m) {
            const float vh = vs[m][h];
            const float d  = (glvl + num[m] - (gl + den[m]) * vh) * cinv;
            vs[m][h] = vh + d * DT
                     + gd * noise0[step * (BK * H0) + (bk0 + m) * H0 + h];
        }
        __syncthreads();
    }

    #pragma unroll
    for (int m = 0; m < M0; ++m)
        outp[(bk0 + m) * 256 + h] = vs[m][h];   // s0 -> new_particles[:, :H0]
}

// ---------------------------------------------------------------------------
// K3: layer-1 fused input-synapse + unfold. Input is s0 (per-particle, but
// invariant across the 6 steps). 256 blocks x 64 threads x M1=4 rows.
constexpr int M1 = 4;
__global__ __launch_bounds__(H1) void l1_unfold_kernel(
    const float* __restrict__ particles,  // [BK, 256]
    const float* __restrict__ noise1,     // [UNF, BK, H1]
    const float* __restrict__ gleak1,     // [H1]
    const float* __restrict__ vleak1,
    const float* __restrict__ cm1,
    const float* __restrict__ iw1,        // [H0, H1]
    const float* __restrict__ isig1,
    const float* __restrict__ imu1,
    const float* __restrict__ ierev1,
    const float* __restrict__ w1,         // [H1, H1]
    const float* __restrict__ sig1,
    const float* __restrict__ mu1,
    const float* __restrict__ erev1,
    const float* __restrict__ gdiff1,     // [H1]
    float* __restrict__ outp)             // new_particles region: [BK, 256]
{
    const int h   = threadIdx.x;          // 0..63
    const int bk0 = blockIdx.x * M1;

    __shared__ float v0s[M1][H0];
    __shared__ float v1s[M1][H1];
    #pragma unroll
    for (int m = 0; m < M1; ++m) {
        v0s[m][h]       = outp[(bk0 + m) * 256 + h];        // s0 written by K2
        v0s[m][h + 64]  = outp[(bk0 + m) * 256 + h + 64];
        v0s[m][h + 128] = outp[(bk0 + m) * 256 + h + 128];
        v1s[m][h]       = particles[(bk0 + m) * 256 + H0 + h];
    }
    __syncthreads();

    // Input synapse sums over s0 (step-invariant)
    float innum[M1], inden[M1];
    #pragma unroll
    for (int m = 0; m < M1; ++m) { innum[m] = 0.0f; inden[m] = 0.0f; }
    for (int i = 0; i < H0; ++i) {
        const int idx = i * H1 + h;
        const float wv = fmaxf(iw1[idx], 0.0f);
        const float sg = isig1[idx];
        const float mn = imu1[idx];
        const float er = ierev1[idx];
        #pragma unroll
        for (int m = 0; m < M1; ++m) {
            const float a = wv * fast_sigmoid(sg * (v0s[m][i] - mn));
            innum[m] = fmaf(a, er, innum[m]);
            inden[m] += a;
        }
    }

    const float gl   = fmaxf(gleak1[h], 0.0f);
    const float glvl = gl * vleak1[h];
    const float cinv = __builtin_amdgcn_rcpf(fmaxf(cm1[h], 0.0f) + EPS);
    const float gd   = gdiff1[h] * sqrtf(DT);

    for (int step = 0; step < UNF; ++step) {
        float num[M1], den[M1];
        #pragma unroll
        for (int m = 0; m < M1; ++m) { num[m] = innum[m]; den[m] = inden[m]; }

        for (int i = 0; i < H1; ++i) {
            const int idx = i * H1 + h;
            const float wv = fmaxf(w1[idx], 0.0f);
            const float sg = sig1[idx];
            const float mn = mu1[idx];
            const float er = erev1[idx];
            #pragma unroll
            for (int m = 0; m < M1; ++m) {
                const float a = wv * fast_sigmoid(sg * (v1s[m][i] - mn));
                num[m] = fmaf(a, er, num[m]);
                den[m] += a;
            }
        }
        __syncthreads();
        #pragma unroll
        for (int m = 0; m < M1; ++m) {
            const float vh = v1s[m][h];
            const float d  = (glvl + num[m] - (gl + den[m]) * vh) * cinv;
            v1s[m][h] = vh + d * DT
                      + gd * noise1[step * (BK * H1) + (bk0 + m) * H1 + h];
        }
        __syncthreads();
    }

    #pragma unroll
    for (int m = 0; m < M1; ++m)
        outp[(bk0 + m) * 256 + H0 + h] = v1s[m][h];  // s1 -> new_particles[:, H0:]
}

// ---------------------------------------------------------------------------
// K4: output = softmax(log_weights) weighted mean of s1 over K; also pass
// log_weights through. grid: B blocks x 64 threads (one wave).
__global__ __launch_bounds__(64) void finalize_kernel(
    const float* __restrict__ log_weights,  // [B, K]
    const float* __restrict__ newp,         // new_particles region [BK,256]
    float* __restrict__ out_y,              // [B, H1]
    float* __restrict__ out_lw)             // [B, K]
{
    const int t = threadIdx.x;   // used as k, then as h (K == H1 == 64)
    const int b = blockIdx.x;

    const float lw = log_weights[b * K + t];
    out_lw[b * K + t] = lw;

    float mx = lw;
    #pragma unroll
    for (int o = 32; o > 0; o >>= 1) mx = fmaxf(mx, __shfl_xor(mx, o));
    const float e = __expf(lw - mx);
    float s = e;
    #pragma unroll
    for (int o = 32; o > 0; o >>= 1) s += __shfl_xor(s, o);

    __shared__ float wk[K];
    wk[t] = e / s;
    __syncthreads();

    float acc = 0.0f;
    for (int k = 0; k < K; ++k)
        acc = fmaf(wk[k], newp[(b * K + k) * 256 + H0 + t], acc);
    out_y[b * H1 + t] = acc;
}

// ---------------------------------------------------------------------------
extern "C" void kernel_launch(void* const* d_in, const int* in_sizes, int n_in,
                              void* d_out, int out_size, void* d_ws, size_t ws_size,
                              hipStream_t stream) {
    const float* x           = (const float*)d_in[0];
    const float* particles   = (const float*)d_in[1];
    const float* log_weights = (const float*)d_in[2];
    const float* noise0      = (const float*)d_in[3];
    const float* noise1      = (const float*)d_in[4];
    const float* gleak0 = (const float*)d_in[5];
    const float* vleak0 = (const float*)d_in[6];
    const float* cm0    = (const float*)d_in[7];
    const float* iw0    = (const float*)d_in[8];
    const float* isig0  = (const float*)d_in[9];
    const float* imu0   = (const float*)d_in[10];
    const float* ierev0 = (const float*)d_in[11];
    const float* w0     = (const float*)d_in[12];
    const float* sig0   = (const float*)d_in[13];
    const float* mu0    = (const float*)d_in[14];
    const float* erev0  = (const float*)d_in[15];
    const float* gdiff0 = (const float*)d_in[16];
    const float* gleak1 = (const float*)d_in[17];
    const float* vleak1 = (const float*)d_in[18];
    const float* cm1    = (const float*)d_in[19];
    const float* iw1    = (const float*)d_in[20];
    const float* isig1  = (const float*)d_in[21];
    const float* imu1   = (const float*)d_in[22];
    const float* ierev1 = (const float*)d_in[23];
    const float* w1     = (const float*)d_in[24];
    const float* sig1   = (const float*)d_in[25];
    const float* mu1    = (const float*)d_in[26];
    const float* erev1  = (const float*)d_in[27];
    const float* gdiff1 = (const float*)d_in[28];

    float* out   = (float*)d_out;
    float* out_y  = out;                       // [B, H1] = 1024
    float* out_np = out + B * H1;              // [BK, 256] = 262144
    float* out_lw = out + B * H1 + BK * 256;   // [B, K]   = 1024

    float* in_num0 = (float*)d_ws;             // [B, H0]
    float* in_den0 = in_num0 + B * H0;         // [B, H0]

    l0_input_kernel<<<B, H0, 0, stream>>>(x, iw0, isig0, imu0, ierev0,
                                          in_num0, in_den0);

    l0_unfold_kernel<<<BK / M0, H0, 0, stream>>>(
        particles, noise0, gleak0, vleak0, cm0, w0, sig0, mu0, erev0, gdiff0,
        in_num0, in_den0, out_np);

    l1_unfold_kernel<<<BK / M1, H1, 0, stream>>>(
        particles, noise1, gleak1, vleak1, cm1, iw1, isig1, imu1, ierev1,
        w1, sig1, mu1, erev1, gdiff1, out_np);

    finalize_kernel<<<B, 64, 0, stream>>>(log_weights, out_np, out_y, out_lw);
}

// Round 2
// 265.295 us; speedup vs baseline: 1.5269x; 1.5269x over previous
//
#include <hip/hip_runtime.h>
#include <math.h>

// Problem dims
constexpr int B   = 16;
constexpr int K   = 64;
constexpr int BK  = B * K;        // 1024
constexpr int IN  = 128;
constexpr int H0  = 192;
constexpr int H1  = 64;
constexpr int UNF = 6;
constexpr float EPS = 1e-8f;
constexpr float DT  = 1.0f / 6.0f;
constexpr float L2E = 1.4426950408889634f;   // log2(e)

static __device__ __forceinline__ float rcpf(float x) {
    return __builtin_amdgcn_rcpf(x);
}
static __device__ __forceinline__ float exp2_fast(float x) {
#if __has_builtin(__builtin_amdgcn_exp2f)
    return __builtin_amdgcn_exp2f(x);   // v_exp_f32
#else
    return exp2f(x);
#endif
}
// sigmoid(z) with z pre-scaled by log2(e): s = 1/(1+2^(-z2))
static __device__ __forceinline__ float sig_from_t(float t /* = -z2 */) {
    return rcpf(1.0f + exp2_fast(t));
}

// ---------------------------------------------------------------------------
// K0: pack {relu(w), sig*L2E, sig*mu*L2E, relu(w)*erev} into float4 for the
// three recurrent/input matrices swept in the hot loops. One dwordx4 load
// replaces 4 scalar loads; exp argument becomes a single fmaf.
__global__ __launch_bounds__(256) void pack_kernel(
    const float* __restrict__ w0,  const float* __restrict__ sig0,
    const float* __restrict__ mu0, const float* __restrict__ erev0,
    const float* __restrict__ iw1, const float* __restrict__ isig1,
    const float* __restrict__ imu1,const float* __restrict__ ierev1,
    const float* __restrict__ w1,  const float* __restrict__ sig1,
    const float* __restrict__ mu1, const float* __restrict__ erev1,
    float4* __restrict__ pack0, float4* __restrict__ packi1,
    float4* __restrict__ pack1)
{
    const int t = blockIdx.x * 256 + threadIdx.x;
    constexpr int N0 = H0 * H0;          // 36864
    constexpr int N1 = H0 * H1;          // 12288
    constexpr int N2 = H1 * H1;          // 4096
    if (t < N0) {
        const float wv = fmaxf(w0[t], 0.0f);
        pack0[t] = make_float4(wv, sig0[t] * L2E, sig0[t] * mu0[t] * L2E,
                               wv * erev0[t]);
    } else if (t < N0 + N1) {
        const int u = t - N0;
        const float wv = fmaxf(iw1[u], 0.0f);
        packi1[u] = make_float4(wv, isig1[u] * L2E, isig1[u] * imu1[u] * L2E,
                                wv * ierev1[u]);
    } else if (t < N0 + N1 + N2) {
        const int u = t - N0 - N1;
        const float wv = fmaxf(w1[u], 0.0f);
        pack1[u] = make_float4(wv, sig1[u] * L2E, sig1[u] * mu1[u] * L2E,
                               wv * erev1[u]);
    }
}

// ---------------------------------------------------------------------------
// K1: layer-0 input synapse sums. x is shared by all K particles and all 6
// unfold steps -> only [B,H0] = 16x192 work. grid: B blocks x H0 threads.
__global__ __launch_bounds__(H0) void l0_input_kernel(
    const float* __restrict__ x,      // [B, IN]
    const float* __restrict__ iw0,    // [IN, H0]
    const float* __restrict__ isig0,
    const float* __restrict__ imu0,
    const float* __restrict__ ierev0,
    float* __restrict__ in_num,       // [B, H0]
    float* __restrict__ in_den)       // [B, H0]
{
    const int h = threadIdx.x;
    const int b = blockIdx.x;
    __shared__ float xs[IN];
    if (h < IN) xs[h] = x[b * IN + h];
    __syncthreads();

    float num = 0.0f, den = 0.0f;
    #pragma unroll 4
    for (int i = 0; i < IN; ++i) {
        const int idx = i * H0 + h;
        const float wv = fmaxf(iw0[idx], 0.0f);
        const float t  = isig0[idx] * L2E * (imu0[idx] - xs[i]);
        const float a  = wv * sig_from_t(t);
        num = fmaf(a, ierev0[idx], num);
        den += a;
    }
    in_num[b * H0 + h] = num;
    in_den[b * H0 + h] = den;
}

// ---------------------------------------------------------------------------
// K2: layer-0 unfold. 256 blocks x 768 threads (4 row-subgroups x 192h).
// Each 192-thread subgroup owns one particle row -> 12 waves/CU, and the 4
// subgroups read identical pack0 addresses in near-lockstep (L1 dedup), so
// L2 param traffic stays at 256 row-groups x 6 steps x 590KB ~ 0.9 GB.
__global__ __launch_bounds__(768) void l0_unfold_kernel(
    const float* __restrict__ particles,  // [BK, 256]
    const float* __restrict__ noise0,     // [UNF, BK, H0]
    const float* __restrict__ gleak0,     // [H0]
    const float* __restrict__ vleak0,
    const float* __restrict__ cm0,
    const float* __restrict__ gdiff0,
    const float4* __restrict__ pack0,     // [H0*H0]
    const float* __restrict__ in_num,     // [B, H0]
    const float* __restrict__ in_den,
    float* __restrict__ outp)             // new_particles region: [BK, 256]
{
    const int h  = threadIdx.x % H0;      // 0..191
    const int r  = threadIdx.x / H0;      // 0..3 (row subgroup, 3 whole waves)
    const int bk = blockIdx.x * 4 + r;
    const int b  = blockIdx.x >> 4;       // (blockIdx.x*4)/64

    __shared__ float vs[4][H0];
    vs[r][h] = particles[bk * 256 + h];

    float nz[UNF];
    #pragma unroll
    for (int s = 0; s < UNF; ++s)
        nz[s] = noise0[s * (BK * H0) + bk * H0 + h];

    const float gl    = fmaxf(gleak0[h], 0.0f);
    const float glvl  = gl * vleak0[h];
    const float cinv  = rcpf(fmaxf(cm0[h], 0.0f) + EPS);
    const float gd    = gdiff0[h] * sqrtf(DT);
    const float innum = in_num[b * H0 + h];
    const float inden = in_den[b * H0 + h];
    __syncthreads();

    for (int step = 0; step < UNF; ++step) {
        float num = innum, den = inden;
        #pragma unroll 8
        for (int i = 0; i < H0; ++i) {
            const float4 p = pack0[i * H0 + h];     // {wv, sig', smu', wv*er}
            const float  v = vs[r][i];              // LDS broadcast per wave
            const float  s = sig_from_t(fmaf(-p.y, v, p.z));
            num = fmaf(s, p.w, num);
            den = fmaf(s, p.x, den);
        }
        __syncthreads();   // all reads of vs[r][*] done
        const float vh = vs[r][h];
        const float d  = (glvl + num - (gl + den) * vh) * cinv;
        vs[r][h] = fmaf(gd, nz[step], fmaf(d, DT, vh));
        __syncthreads();
    }

    outp[bk * 256 + h] = vs[r][h];        // s0 -> new_particles[:, :H0]
}

// ---------------------------------------------------------------------------
// K3: layer-1 fused input-synapse + unfold. 256 blocks x 1024 threads:
// 4 rows x 4-way i-split x 64h -> 16 waves/CU. Partials combined in LDS each
// step; quarter 0 applies the state update.
__global__ __launch_bounds__(1024) void l1_unfold_kernel(
    const float* __restrict__ particles,  // [BK, 256]
    const float* __restrict__ noise1,     // [UNF, BK, H1]
    const float* __restrict__ gleak1,     // [H1]
    const float* __restrict__ vleak1,
    const float* __restrict__ cm1,
    const float* __restrict__ gdiff1,
    const float4* __restrict__ packi1,    // [H0*H1]
    const float4* __restrict__ pack1,     // [H1*H1]
    float* __restrict__ outp)             // new_particles region: [BK, 256]
{
    const int t   = threadIdx.x;
    const int h   = t & 63;
    const int sub = t >> 6;               // wave id 0..15
    const int m   = sub >> 2;             // row 0..3
    const int q   = sub & 3;              // i-split quarter
    const int bk0 = blockIdx.x * 4;

    __shared__ float v0s[4][H0];
    __shared__ float v1s[4][H1];
    __shared__ float part[4][4][H1][2];

    if (t < 4 * H0) {                     // 768 loads of s0 (written by K2)
        const int mm = t / H0, ii = t % H0;
        v0s[mm][ii] = outp[(bk0 + mm) * 256 + ii];
    } else {                              // 256 loads of v1
        const int u = t - 4 * H0;
        const int mm = u >> 6, hh = u & 63;
        v1s[mm][hh] = particles[(bk0 + mm) * 256 + H0 + hh];
    }
    __syncthreads();

    // Input-synapse partial over i in [q*48, q*48+48) — step-invariant.
    float innum = 0.0f, inden = 0.0f;
    #pragma unroll 4
    for (int i = q * 48; i < q * 48 + 48; ++i) {
        const float4 p = packi1[i * H1 + h];
        const float  s = sig_from_t(fmaf(-p.y, v0s[m][i], p.z));
        innum = fmaf(s, p.w, innum);
        inden = fmaf(s, p.x, inden);
    }

    const float gl   = fmaxf(gleak1[h], 0.0f);
    const float glvl = gl * vleak1[h];
    const float cinv = rcpf(fmaxf(cm1[h], 0.0f) + EPS);
    const float gd   = gdiff1[h] * sqrtf(DT);
    float nz[UNF];
    if (q == 0) {
        #pragma unroll
        for (int s = 0; s < UNF; ++s)
            nz[s] = noise1[s * (BK * H1) + (bk0 + m) * H1 + h];
    }

    for (int step = 0; step < UNF; ++step) {
        float num = innum, den = inden;   // each quarter carries its own
        #pragma unroll 8
        for (int i = q * 16; i < q * 16 + 16; ++i) {
            const float4 p = pack1[i * H1 + h];
            const float  s = sig_from_t(fmaf(-p.y, v1s[m][i], p.z));
            num = fmaf(s, p.w, num);
            den = fmaf(s, p.x, den);
        }
        part[m][q][h][0] = num;
        part[m][q][h][1] = den;
        __syncthreads();                  // partials visible; v1s reads done
        if (q == 0) {                     // wave-uniform branch
            const float nsum = part[m][0][h][0] + part[m][1][h][0]
                             + part[m][2][h][0] + part[m][3][h][0];
            const float dsum = part[m][0][h][1] + part[m][1][h][1]
                             + part[m][2][h][1] + part[m][3][h][1];
            const float vh = v1s[m][h];
            const float d  = (glvl + nsum - (gl + dsum) * vh) * cinv;
            v1s[m][h] = fmaf(gd, nz[step], fmaf(d, DT, vh));
        }
        __syncthreads();
    }

    if (q == 0)
        outp[(bk0 + m) * 256 + H0 + h] = v1s[m][h];  // s1 -> [:, H0:]
}

// ---------------------------------------------------------------------------
// K4: output = softmax(log_weights) weighted mean of s1 over K; pass
// log_weights through. grid: B blocks x 64 threads (one wave).
__global__ __launch_bounds__(64) void finalize_kernel(
    const float* __restrict__ log_weights,  // [B, K]
    const float* __restrict__ newp,         // new_particles region [BK,256]
    float* __restrict__ out_y,              // [B, H1]
    float* __restrict__ out_lw)             // [B, K]
{
    const int t = threadIdx.x;   // used as k, then as h (K == H1 == 64)
    const int b = blockIdx.x;

    const float lw = log_weights[b * K + t];
    out_lw[b * K + t] = lw;

    float mx = lw;
    #pragma unroll
    for (int o = 32; o > 0; o >>= 1) mx = fmaxf(mx, __shfl_xor(mx, o));
    const float e = __expf(lw - mx);
    float s = e;
    #pragma unroll
    for (int o = 32; o > 0; o >>= 1) s += __shfl_xor(s, o);

    __shared__ float wk[K];
    wk[t] = e / s;
    __syncthreads();

    float acc = 0.0f;
    for (int k = 0; k < K; ++k)
        acc = fmaf(wk[k], newp[(b * K + k) * 256 + H0 + t], acc);
    out_y[b * H1 + t] = acc;
}

// ---------------------------------------------------------------------------
extern "C" void kernel_launch(void* const* d_in, const int* in_sizes, int n_in,
                              void* d_out, int out_size, void* d_ws, size_t ws_size,
                              hipStream_t stream) {
    const float* x           = (const float*)d_in[0];
    const float* particles   = (const float*)d_in[1];
    const float* log_weights = (const float*)d_in[2];
    const float* noise0      = (const float*)d_in[3];
    const float* noise1      = (const float*)d_in[4];
    const float* gleak0 = (const float*)d_in[5];
    const float* vleak0 = (const float*)d_in[6];
    const float* cm0    = (const float*)d_in[7];
    const float* iw0    = (const float*)d_in[8];
    const float* isig0  = (const float*)d_in[9];
    const float* imu0   = (const float*)d_in[10];
    const float* ierev0 = (const float*)d_in[11];
    const float* w0     = (const float*)d_in[12];
    const float* sig0   = (const float*)d_in[13];
    const float* mu0    = (const float*)d_in[14];
    const float* erev0  = (const float*)d_in[15];
    const float* gdiff0 = (const float*)d_in[16];
    const float* gleak1 = (const float*)d_in[17];
    const float* vleak1 = (const float*)d_in[18];
    const float* cm1    = (const float*)d_in[19];
    const float* iw1    = (const float*)d_in[20];
    const float* isig1  = (const float*)d_in[21];
    const float* imu1   = (const float*)d_in[22];
    const float* ierev1 = (const float*)d_in[23];
    const float* w1     = (const float*)d_in[24];
    const float* sig1   = (const float*)d_in[25];
    const float* mu1    = (const float*)d_in[26];
    const float* erev1  = (const float*)d_in[27];
    const float* gdiff1 = (const float*)d_in[28];

    float* out    = (float*)d_out;
    float* out_y  = out;                       // [B, H1] = 1024
    float* out_np = out + B * H1;              // [BK, 256] = 262144
    float* out_lw = out + B * H1 + BK * 256;   // [B, K]   = 1024

    // Workspace layout (floats): pack0 | packi1 | pack1 | in_num0 | in_den0
    float* ws      = (float*)d_ws;
    float4* pack0  = (float4*)(ws);                       // 36864 float4
    float4* packi1 = (float4*)(ws + 4 * 36864);           // 12288 float4
    float4* pack1  = (float4*)(ws + 4 * (36864 + 12288)); //  4096 float4
    float*  in_num0 = ws + 4 * (36864 + 12288 + 4096);    // [B, H0]
    float*  in_den0 = in_num0 + B * H0;                   // [B, H0]

    constexpr int NPACK = H0 * H0 + H0 * H1 + H1 * H1;    // 53248
    pack_kernel<<<(NPACK + 255) / 256, 256, 0, stream>>>(
        w0, sig0, mu0, erev0, iw1, isig1, imu1, ierev1, w1, sig1, mu1, erev1,
        pack0, packi1, pack1);

    l0_input_kernel<<<B, H0, 0, stream>>>(x, iw0, isig0, imu0, ierev0,
                                          in_num0, in_den0);

    l0_unfold_kernel<<<BK / 4, 768, 0, stream>>>(
        particles, noise0, gleak0, vleak0, cm0, gdiff0,
        pack0, in_num0, in_den0, out_np);

    l1_unfold_kernel<<<BK / 4, 1024, 0, stream>>>(
        particles, noise1, gleak1, vleak1, cm1, gdiff1,
        packi1, pack1, out_np);

    finalize_kernel<<<B, 64, 0, stream>>>(log_weights, out_np, out_y, out_lw);
}

// Round 3
// 205.917 us; speedup vs baseline: 1.9672x; 1.2884x over previous
//
#include <hip/hip_runtime.h>
#include <math.h>

// Problem dims
constexpr int B   = 16;
constexpr int K   = 64;
constexpr int BK  = B * K;        // 1024
constexpr int IN  = 128;
constexpr int H0  = 192;
constexpr int H1  = 64;
constexpr int UNF = 6;
constexpr float EPS = 1e-8f;
constexpr float DT  = 1.0f / 6.0f;
constexpr float L2E = 1.4426950408889634f;   // log2(e)

static __device__ __forceinline__ float rcpf(float x) {
    return __builtin_amdgcn_rcpf(x);
}
static __device__ __forceinline__ float exp2_fast(float x) {
#if __has_builtin(__builtin_amdgcn_exp2f)
    return __builtin_amdgcn_exp2f(x);   // v_exp_f32
#else
    return exp2f(x);
#endif
}
// sigmoid(z) with z pre-scaled by log2(e): s = 1/(1+2^(-z2)); t = -z2
static __device__ __forceinline__ float sig_from_t(float t) {
    return rcpf(1.0f + exp2_fast(t));
}

// ---------------------------------------------------------------------------
// Prep: (a) pack {relu(w), sig*L2E, sig*mu*L2E, relu(w)*erev} into float4 for
// the three hot matrices; (b) layer-0 input synapse sums [B,H0] (x is shared
// by all K particles and all 6 steps). One kernel, branch on blockIdx.
constexpr int NPACK    = H0 * H0 + H0 * H1 + H1 * H1;  // 53248
constexpr int NPACKBLK = NPACK / 256;                   // 208
__global__ __launch_bounds__(256) void prep_kernel(
    const float* __restrict__ w0,  const float* __restrict__ sig0,
    const float* __restrict__ mu0, const float* __restrict__ erev0,
    const float* __restrict__ iw1, const float* __restrict__ isig1,
    const float* __restrict__ imu1,const float* __restrict__ ierev1,
    const float* __restrict__ w1,  const float* __restrict__ sig1,
    const float* __restrict__ mu1, const float* __restrict__ erev1,
    const float* __restrict__ x,   const float* __restrict__ iw0,
    const float* __restrict__ isig0,const float* __restrict__ imu0,
    const float* __restrict__ ierev0,
    float4* __restrict__ pack0, float4* __restrict__ packi1,
    float4* __restrict__ pack1,
    float* __restrict__ in_num, float* __restrict__ in_den)
{
    __shared__ float xs[IN];
    if (blockIdx.x < NPACKBLK) {
        const int t = blockIdx.x * 256 + threadIdx.x;
        constexpr int N0 = H0 * H0;          // 36864
        constexpr int N1 = H0 * H1;          // 12288
        if (t < N0) {
            const float wv = fmaxf(w0[t], 0.0f);
            pack0[t] = make_float4(wv, sig0[t] * L2E, sig0[t] * mu0[t] * L2E,
                                   wv * erev0[t]);
        } else if (t < N0 + N1) {
            const int u = t - N0;
            const float wv = fmaxf(iw1[u], 0.0f);
            packi1[u] = make_float4(wv, isig1[u] * L2E,
                                    isig1[u] * imu1[u] * L2E, wv * ierev1[u]);
        } else {
            const int u = t - N0 - N1;
            const float wv = fmaxf(w1[u], 0.0f);
            pack1[u] = make_float4(wv, sig1[u] * L2E, sig1[u] * mu1[u] * L2E,
                                   wv * erev1[u]);
        }
    } else {
        const int b = blockIdx.x - NPACKBLK;
        const int h = threadIdx.x;
        if (h < IN) xs[h] = x[b * IN + h];
        __syncthreads();
        if (h < H0) {
            float num = 0.0f, den = 0.0f;
            #pragma unroll 4
            for (int i = 0; i < IN; ++i) {
                const int idx = i * H0 + h;
                const float wv = fmaxf(iw0[idx], 0.0f);
                const float t  = isig0[idx] * L2E * (imu0[idx] - xs[i]);
                const float a  = wv * sig_from_t(t);
                num = fmaf(a, ierev0[idx], num);
                den += a;
            }
            in_num[b * H0 + h] = num;
            in_den[b * H0 + h] = den;
        }
    }
}

// ---------------------------------------------------------------------------
// Fused unfold: 256 blocks x 768 threads; each block owns 4 particle rows
// end-to-end (layer 0 then layer 1; s0 stays in LDS).
//
// Layer 0: subgroup q (192 threads) handles i in [48q,48q+48) for ALL 4 rows
// -> each pack0 float4 loaded once per block per step (4x less L1 traffic
// than one-subgroup-per-row), state transposed vs[i][4] so one ds_read_b128
// yields all 4 rows. Per-step partial num/den reduced via LDS; thread (q,h)
// applies the update for row q.
// Layer 1: waves 0..7 split i 8-ways with the same 4-row register reuse.
__global__ __launch_bounds__(768) void fused_unfold_kernel(
    const float* __restrict__ particles,  // [BK, 256]
    const float* __restrict__ noise0,     // [UNF, BK, H0]
    const float* __restrict__ noise1,     // [UNF, BK, H1]
    const float* __restrict__ gleak0, const float* __restrict__ vleak0,
    const float* __restrict__ cm0,    const float* __restrict__ gdiff0,
    const float* __restrict__ gleak1, const float* __restrict__ vleak1,
    const float* __restrict__ cm1,    const float* __restrict__ gdiff1,
    const float4* __restrict__ pack0,     // [H0*H0]
    const float4* __restrict__ packi1,    // [H0*H1]
    const float4* __restrict__ pack1,     // [H1*H1]
    const float* __restrict__ in_num,     // [B, H0]
    const float* __restrict__ in_den,
    float* __restrict__ outp)             // new_particles region: [BK, 256]
{
    const int tid = threadIdx.x;
    const int h   = tid % H0;             // 0..191
    const int q   = tid / H0;             // 0..3 (i-quarter AND owned row)
    const int bk0 = blockIdx.x * 4;
    const int b   = blockIdx.x >> 4;

    __shared__ __align__(16) float vs[H0][4];     // s0 state, [i][m]
    __shared__ float2 part0[4][4][H0];            // [q][m][h] {num,den}
    __shared__ __align__(16) float v1s[H1][4];    // s1 state, [i][m]
    __shared__ float2 part1[8][4][H1];            // [qq][m][h1]

    // ---- Layer 0 setup ----
    vs[h][q] = particles[(bk0 + q) * 256 + h];
    float nz[UNF];
    #pragma unroll
    for (int s = 0; s < UNF; ++s)
        nz[s] = noise0[s * (BK * H0) + (bk0 + q) * H0 + h];

    const float gl    = fmaxf(gleak0[h], 0.0f);
    const float glvl  = gl * vleak0[h];
    const float cinv  = rcpf(fmaxf(cm0[h], 0.0f) + EPS);
    const float gd    = gdiff0[h] * sqrtf(DT);
    const float innum = in_num[b * H0 + h];
    const float inden = in_den[b * H0 + h];
    __syncthreads();

    // ---- Layer 0 unfold ----
    const int ibase = 48 * q;
    for (int step = 0; step < UNF; ++step) {
        float num[4] = {0.f, 0.f, 0.f, 0.f};
        float den[4] = {0.f, 0.f, 0.f, 0.f};
        #pragma unroll 4
        for (int ii = 0; ii < 48; ++ii) {
            const int i = ibase + ii;
            const float4 p  = pack0[i * H0 + h];   // {wv, sig', smu', wv*er}
            const float4 vv = *(const float4*)&vs[i][0];  // all 4 rows
            #pragma unroll
            for (int m = 0; m < 4; ++m) {
                const float v = (m == 0) ? vv.x : (m == 1) ? vv.y
                              : (m == 2) ? vv.z : vv.w;
                const float s = sig_from_t(fmaf(-p.y, v, p.z));
                num[m] = fmaf(s, p.w, num[m]);
                den[m] = fmaf(s, p.x, den[m]);
            }
        }
        #pragma unroll
        for (int m = 0; m < 4; ++m)
            part0[q][m][h] = make_float2(num[m], den[m]);
        __syncthreads();
        // thread (q,h) updates row q, element h
        float tn = innum, td = inden;
        #pragma unroll
        for (int j = 0; j < 4; ++j) {
            const float2 t = part0[j][q][h];
            tn += t.x; td += t.y;
        }
        const float vh = vs[h][q];
        const float d  = (glvl + tn - (gl + td) * vh) * cinv;
        vs[h][q] = fmaf(gd, nz[step], fmaf(d, DT, vh));
        __syncthreads();
    }

    // s0 -> new_particles[:, :H0]
    outp[(bk0 + q) * 256 + h] = vs[h][q];

    // ---- Layer 1 (same 4 rows; s0 in LDS) ----
    const int h1 = tid & 63;
    const int qq = tid >> 6;              // wave id 0..11; 0..7 active
    float nz1[UNF];
    if (tid < 256) {                      // qq == row m for the update phase
        v1s[h1][qq] = particles[(bk0 + qq) * 256 + H0 + h1];
        #pragma unroll
        for (int s = 0; s < UNF; ++s)
            nz1[s] = noise1[s * (BK * H1) + (bk0 + qq) * H1 + h1];
    }

    float gl1 = 0.f, glvl1 = 0.f, cinv1 = 0.f, gd1 = 0.f;
    float in1n[4] = {0.f, 0.f, 0.f, 0.f};
    float in1d[4] = {0.f, 0.f, 0.f, 0.f};
    if (tid < 512) {
        gl1   = fmaxf(gleak1[h1], 0.0f);
        glvl1 = gl1 * vleak1[h1];
        cinv1 = rcpf(fmaxf(cm1[h1], 0.0f) + EPS);
        gd1   = gdiff1[h1] * sqrtf(DT);
        // input synapse over s0: i in [24qq, 24qq+24), step-invariant
        #pragma unroll 4
        for (int ii = 0; ii < 24; ++ii) {
            const int i = qq * 24 + ii;
            const float4 p  = packi1[i * H1 + h1];
            const float4 vv = *(const float4*)&vs[i][0];
            #pragma unroll
            for (int m = 0; m < 4; ++m) {
                const float v = (m == 0) ? vv.x : (m == 1) ? vv.y
                              : (m == 2) ? vv.z : vv.w;
                const float s = sig_from_t(fmaf(-p.y, v, p.z));
                in1n[m] = fmaf(s, p.w, in1n[m]);
                in1d[m] = fmaf(s, p.x, in1d[m]);
            }
        }
    }
    __syncthreads();   // v1s visible

    for (int step = 0; step < UNF; ++step) {
        if (tid < 512) {
            float num[4], den[4];
            #pragma unroll
            for (int m = 0; m < 4; ++m) { num[m] = in1n[m]; den[m] = in1d[m]; }
            #pragma unroll
            for (int ii = 0; ii < 8; ++ii) {
                const int i = qq * 8 + ii;
                const float4 p  = pack1[i * H1 + h1];
                const float4 vv = *(const float4*)&v1s[i][0];
                #pragma unroll
                for (int m = 0; m < 4; ++m) {
                    const float v = (m == 0) ? vv.x : (m == 1) ? vv.y
                                  : (m == 2) ? vv.z : vv.w;
                    const float s = sig_from_t(fmaf(-p.y, v, p.z));
                    num[m] = fmaf(s, p.w, num[m]);
                    den[m] = fmaf(s, p.x, den[m]);
                }
            }
            #pragma unroll
            for (int m = 0; m < 4; ++m)
                part1[qq][m][h1] = make_float2(num[m], den[m]);
        }
        __syncthreads();
        if (tid < 256) {                  // row qq, element h1
            float tn = 0.f, td = 0.f;
            #pragma unroll
            for (int j = 0; j < 8; ++j) {
                const float2 t = part1[j][qq][h1];
                tn += t.x; td += t.y;
            }
            const float vh = v1s[h1][qq];
            const float d  = (glvl1 + tn - (gl1 + td) * vh) * cinv1;
            v1s[h1][qq] = fmaf(gd1, nz1[step], fmaf(d, DT, vh));
        }
        __syncthreads();
    }

    if (tid < 256)
        outp[(bk0 + qq) * 256 + H0 + h1] = v1s[h1][qq];  // s1 -> [:, H0:]
}

// ---------------------------------------------------------------------------
// Finalize: output = softmax(log_weights) weighted mean of s1 over K; pass
// log_weights through. grid: B blocks x 64 threads (one wave).
__global__ __launch_bounds__(64) void finalize_kernel(
    const float* __restrict__ log_weights,  // [B, K]
    const float* __restrict__ newp,         // new_particles region [BK,256]
    float* __restrict__ out_y,              // [B, H1]
    float* __restrict__ out_lw)             // [B, K]
{
    const int t = threadIdx.x;   // used as k, then as h (K == H1 == 64)
    const int b = blockIdx.x;

    const float lw = log_weights[b * K + t];
    out_lw[b * K + t] = lw;

    float mx = lw;
    #pragma unroll
    for (int o = 32; o > 0; o >>= 1) mx = fmaxf(mx, __shfl_xor(mx, o));
    const float e = __expf(lw - mx);
    float s = e;
    #pragma unroll
    for (int o = 32; o > 0; o >>= 1) s += __shfl_xor(s, o);

    __shared__ float wk[K];
    wk[t] = e / s;
    __syncthreads();

    float acc = 0.0f;
    for (int k = 0; k < K; ++k)
        acc = fmaf(wk[k], newp[(b * K + k) * 256 + H0 + t], acc);
    out_y[b * H1 + t] = acc;
}

// ---------------------------------------------------------------------------
extern "C" void kernel_launch(void* const* d_in, const int* in_sizes, int n_in,
                              void* d_out, int out_size, void* d_ws, size_t ws_size,
                              hipStream_t stream) {
    const float* x           = (const float*)d_in[0];
    const float* particles   = (const float*)d_in[1];
    const float* log_weights = (const float*)d_in[2];
    const float* noise0      = (const float*)d_in[3];
    const float* noise1      = (const float*)d_in[4];
    const float* gleak0 = (const float*)d_in[5];
    const float* vleak0 = (const float*)d_in[6];
    const float* cm0    = (const float*)d_in[7];
    const float* iw0    = (const float*)d_in[8];
    const float* isig0  = (const float*)d_in[9];
    const float* imu0   = (const float*)d_in[10];
    const float* ierev0 = (const float*)d_in[11];
    const float* w0     = (const float*)d_in[12];
    const float* sig0   = (const float*)d_in[13];
    const float* mu0    = (const float*)d_in[14];
    const float* erev0  = (const float*)d_in[15];
    const float* gdiff0 = (const float*)d_in[16];
    const float* gleak1 = (const float*)d_in[17];
    const float* vleak1 = (const float*)d_in[18];
    const float* cm1    = (const float*)d_in[19];
    const float* iw1    = (const float*)d_in[20];
    const float* isig1  = (const float*)d_in[21];
    const float* imu1   = (const float*)d_in[22];
    const float* ierev1 = (const float*)d_in[23];
    const float* w1     = (const float*)d_in[24];
    const float* sig1   = (const float*)d_in[25];
    const float* mu1    = (const float*)d_in[26];
    const float* erev1  = (const float*)d_in[27];
    const float* gdiff1 = (const float*)d_in[28];

    float* out    = (float*)d_out;
    float* out_y  = out;                       // [B, H1] = 1024
    float* out_np = out + B * H1;              // [BK, 256] = 262144
    float* out_lw = out + B * H1 + BK * 256;   // [B, K]   = 1024

    // Workspace layout (floats): pack0 | packi1 | pack1 | in_num0 | in_den0
    float* ws      = (float*)d_ws;
    float4* pack0  = (float4*)(ws);                       // 36864 float4
    float4* packi1 = (float4*)(ws + 4 * 36864);           // 12288 float4
    float4* pack1  = (float4*)(ws + 4 * (36864 + 12288)); //  4096 float4
    float*  in_num0 = ws + 4 * (36864 + 12288 + 4096);    // [B, H0]
    float*  in_den0 = in_num0 + B * H0;                   // [B, H0]

    prep_kernel<<<NPACKBLK + B, 256, 0, stream>>>(
        w0, sig0, mu0, erev0, iw1, isig1, imu1, ierev1, w1, sig1, mu1, erev1,
        x, iw0, isig0, imu0, ierev0,
        pack0, packi1, pack1, in_num0, in_den0);

    fused_unfold_kernel<<<BK / 4, 768, 0, stream>>>(
        particles, noise0, noise1,
        gleak0, vleak0, cm0, gdiff0,
        gleak1, vleak1, cm1, gdiff1,
        pack0, packi1, pack1, in_num0, in_den0, out_np);

    finalize_kernel<<<B, 64, 0, stream>>>(log_weights, out_np, out_y, out_lw);
}